// Round 2
// baseline (96.228 us; speedup 1.0000x reference)
//
#include <hip/hip_runtime.h>

// FAPELoss = fape + 0.05*clash + 0.3*physics  ->  single f32 scalar.
// Harness-fixed shapes: B=2, R=1024, A=4096, 19 vdw radii.
//
// Two dispatches:
//   fat_kernel: blocks [0,512) FAPE | [512,1024) pair-band | [1024,1792) pair-full
//               -> per-block float partials in ws (written unconditionally; no memset needed)
//   finalize_kernel: 1 block; sums partials + type counts + mask sums -> out[0]
//
// Pair symmetry: d(i,j) bit-symmetric in the reference (commutative adds, identical
// dot order), so each unordered pair is evaluated once: clash weight 2 (band blocks
// use per-pair i<j / i==j weights), pen adds BOTH ordered CN terms via the scalar
// j-class branch (j==N -> pp*cf_i, j==C -> pp*nf_i).
// Clash uses d2 < mind^2 (== d < mind up to sqrt-rounding ties; ~1e-6/pair flip prob,
// 6e-6 output impact each). (d > EPS) is vacuous: d >= sqrt(1e-12) = 1e-6 > 1e-8.

constexpr int BB = 2;
constexpr int FR = 4;     // frames per FAPE block
constexpr int NI = 4;     // i-atoms per thread (pair)
constexpr int TJ = 16;    // j-tile (pair)
constexpr int IC = 1024;  // i-chunk (pair)

constexpr int NB_FAPE = 512;  // BB * R / FR
constexpr int NB_BAND = 512;  // BB * (A/IC) * (IC/TJ) = 2*4*64
constexpr int NB_FULL = 768;  // BB * (192+128+64+0)
constexpr int NB_PAIR = NB_BAND + NB_FULL;

__device__ __forceinline__ float wred(float v) {
#pragma unroll
  for (int o = 32; o > 0; o >>= 1) v += __shfl_down(v, o, 64);
  return v;
}
__device__ __forceinline__ double wredd(double v) {
#pragma unroll
  for (int o = 32; o > 0; o >>= 1) v += __shfl_down(v, o, 64);
  return v;
}

// ---------------- pair body (no LDS: j-atom is wave-uniform -> SGPR broadcast) ----
template <bool BAND>
__device__ __forceinline__ void pair_body(
    const float* __restrict__ coords, const int* __restrict__ types,
    const float* __restrict__ vdw, int A, int b, int ic, int jt, int tid,
    float& out_clash, float& out_pen) {
  const int ibase = ic * IC;
  float xi[NI], yi[NI], zi[NI], qi[NI], ri[NI], cf[NI], nf[NI];
  int ii[NI];
#pragma unroll
  for (int k = 0; k < NI; ++k) {
    ii[k] = ibase + (k << 8) + tid;
    const size_t g = (size_t)b * A + ii[k];
    const float x = coords[g * 3], y = coords[g * 3 + 1], z = coords[g * 3 + 2];
    const int t = types[g];
    xi[k] = x; yi[k] = y; zi[k] = z;
    // match reference sq = ((x*x + y*y) + z*z) without fma contraction
    qi[k] = __fadd_rn(__fadd_rn(__fmul_rn(x, x), __fmul_rn(y, y)), __fmul_rn(z, z));
    ri[k] = vdw[t];
    cf[k] = (t == 0) ? 1.f : 0.f;
    nf[k] = (t == 1) ? 1.f : 0.f;
  }

  int cnt2 = 0, cnt1 = 0;
  float pen = 0.f;
  const int j0 = jt * TJ;
#pragma unroll 4
  for (int jj = 0; jj < TJ; ++jj) {
    const int j = j0 + jj;
    const size_t jg = (size_t)b * A + j;   // uniform -> scalar loads
    const float sx = coords[jg * 3], sy = coords[jg * 3 + 1], sz = coords[jg * 3 + 2];
    const int st = types[jg];
    const float sr = vdw[st];
    const float sq = __fadd_rn(__fadd_rn(__fmul_rn(sx, sx), __fmul_rn(sy, sy)),
                               __fmul_rn(sz, sz));
    float dsq[NI];
#pragma unroll
    for (int k = 0; k < NI; ++k) {
      const float dot = fmaf(zi[k], sz, fmaf(yi[k], sy, xi[k] * sx));
      float d2 = fmaf(-2.f, dot, qi[k] + sq);
      d2 = fmaxf(d2, 1e-12f);
      dsq[k] = d2;
      const float mind = ri[k] + sr;
      const bool c = d2 < mind * mind;
      if (BAND) {
        cnt2 += (c && (ii[k] < j)) ? 1 : 0;
        cnt1 += (c && (ii[k] == j)) ? 1 : 0;
      } else {
        cnt2 += c ? 1 : 0;
      }
    }
    if (st <= 1) {  // j is C (0) or N (1): uniform branch, ~10.5% of j's
      if (st == 1) {
#pragma unroll
        for (int k = 0; k < NI; ++k) {
          const float dd = __builtin_amdgcn_sqrtf(dsq[k]);
          float pp = fmaxf(fabsf(dd - 1.33f) - 0.2f, 0.f);
          if (BAND) pp = (ii[k] < j) ? pp : 0.f;
          pen = fmaf(pp, cf[k], pen);  // ordered (i=C, j=N) term
        }
      } else {
#pragma unroll
        for (int k = 0; k < NI; ++k) {
          const float dd = __builtin_amdgcn_sqrtf(dsq[k]);
          float pp = fmaxf(fabsf(dd - 1.33f) - 0.2f, 0.f);
          if (BAND) pp = (ii[k] < j) ? pp : 0.f;
          pen = fmaf(pp, nf[k], pen);  // ordered (j=C, i=N) term
        }
      }
    }
  }
  out_clash = 2.f * cnt2 + (float)cnt1;
  out_pen = pen;
}

// ---------------- fused kernel --------------------------------------------------
__global__ __launch_bounds__(256) void fat_kernel(
    const float* __restrict__ rots_p, const float* __restrict__ trans_p,
    const float* __restrict__ coords_p,
    const float* __restrict__ rots_t, const float* __restrict__ trans_t,
    const float* __restrict__ coords_t,
    const int* __restrict__ types, const float* __restrict__ vdw,
    const float* __restrict__ res_mask, const float* __restrict__ mask,
    float* __restrict__ fape_part, float* __restrict__ clash_part,
    float* __restrict__ pen_part, int R, int A) {
  const int tid = threadIdx.x;
  const int bid = blockIdx.x;
  __shared__ float red[2][4];

  if (bid < NB_FAPE) {
    // ---- FAPE: err = min(||Rp^T x - Rt^T y - c||_{+eps}, 10) * mask * res_mask
    const int bpb = R / FR;                 // 256 blocks per batch
    const int b = bid / bpb;
    const int r0 = (bid % bpb) * FR;

    float rp[FR][9], rt[FR][9], cc[FR][3], rm[FR];
#pragma unroll
    for (int f = 0; f < FR; ++f) {
      const size_t fr = (size_t)(b * R + r0 + f);  // uniform -> s_load
      const float* Rp = rots_p + fr * 9;
      const float* Rt = rots_t + fr * 9;
      const float* Tp = trans_p + fr * 3;
      const float* Tt = trans_t + fr * 3;
#pragma unroll
      for (int k = 0; k < 9; ++k) { rp[f][k] = Rp[k]; rt[f][k] = Rt[k]; }
      const float tp0 = Tp[0], tp1 = Tp[1], tp2 = Tp[2];
      const float tt0 = Tt[0], tt1 = Tt[1], tt2 = Tt[2];
#pragma unroll
      for (int i = 0; i < 3; ++i) {
        cc[f][i] = (rp[f][0 + i] * tp0 + rp[f][3 + i] * tp1 + rp[f][6 + i] * tp2)
                 - (rt[f][0 + i] * tt0 + rt[f][3 + i] * tt1 + rt[f][6 + i] * tt2);
      }
      rm[f] = res_mask[fr];
    }

    float facc[FR];
#pragma unroll
    for (int f = 0; f < FR; ++f) facc[f] = 0.f;

    for (int a = tid; a < A; a += 256) {
      const size_t g = (size_t)b * A + a;
      const float x0 = coords_p[g * 3], x1 = coords_p[g * 3 + 1], x2 = coords_p[g * 3 + 2];
      const float y0 = coords_t[g * 3], y1 = coords_t[g * 3 + 1], y2 = coords_t[g * 3 + 2];
      const float m = mask[g];
#pragma unroll
      for (int f = 0; f < FR; ++f) {
        float u0 = fmaf(rp[f][0], x0, -cc[f][0]);
        u0 = fmaf(rp[f][3], x1, u0); u0 = fmaf(rp[f][6], x2, u0);
        u0 = fmaf(-rt[f][0], y0, u0); u0 = fmaf(-rt[f][3], y1, u0); u0 = fmaf(-rt[f][6], y2, u0);
        float u1 = fmaf(rp[f][1], x0, -cc[f][1]);
        u1 = fmaf(rp[f][4], x1, u1); u1 = fmaf(rp[f][7], x2, u1);
        u1 = fmaf(-rt[f][1], y0, u1); u1 = fmaf(-rt[f][4], y1, u1); u1 = fmaf(-rt[f][7], y2, u1);
        float u2 = fmaf(rp[f][2], x0, -cc[f][2]);
        u2 = fmaf(rp[f][5], x1, u2); u2 = fmaf(rp[f][8], x2, u2);
        u2 = fmaf(-rt[f][2], y0, u2); u2 = fmaf(-rt[f][5], y1, u2); u2 = fmaf(-rt[f][8], y2, u2);
        float e2 = fmaf(u0, u0, 1e-8f);
        e2 = fmaf(u1, u1, e2);
        e2 = fmaf(u2, u2, e2);
        float e = __builtin_amdgcn_sqrtf(e2);
        e = fminf(e, 10.0f);
        facc[f] = fmaf(e, m, facc[f]);
      }
    }

    float tot = 0.f;
#pragma unroll
    for (int f = 0; f < FR; ++f) tot = fmaf(facc[f], rm[f], tot);

    tot = wred(tot);
    if ((tid & 63) == 0) red[0][tid >> 6] = tot;
    __syncthreads();
    if (tid == 0) fape_part[bid] = red[0][0] + red[0][1] + red[0][2] + red[0][3];
    return;
  }

  // ---- pair blocks ----
  int b, ic, jt;
  bool band;
  if (bid < NB_FAPE + NB_BAND) {
    const int q = bid - NB_FAPE;
    band = true;
    b = q >> 8;
    const int r = q & 255;
    ic = r >> 6;
    jt = (ic << 6) + (r & 63);        // band: 64*ic <= jt < 64*(ic+1)
  } else {
    const int q = bid - (NB_FAPE + NB_BAND);
    band = false;
    b = q / 384;
    const int r = q % 384;
    if (r < 192)      { ic = 0; jt = 64 + r; }
    else if (r < 320) { ic = 1; jt = 128 + (r - 192); }
    else              { ic = 2; jt = 192 + (r - 320); }
  }

  float oc, op;
  if (band) pair_body<true >(coords_p, types, vdw, A, b, ic, jt, tid, oc, op);
  else      pair_body<false>(coords_p, types, vdw, A, b, ic, jt, tid, oc, op);

  const float rc = wred(oc);
  const float rpn = wred(op);
  if ((tid & 63) == 0) { red[0][tid >> 6] = rc; red[1][tid >> 6] = rpn; }
  __syncthreads();
  if (tid == 0) {
    const int pidx = bid - NB_FAPE;
    clash_part[pidx] = red[0][0] + red[0][1] + red[0][2] + red[0][3];
    pen_part[pidx]   = red[1][0] + red[1][1] + red[1][2] + red[1][3];
  }
}

// ---------------- finalize ------------------------------------------------------
__global__ __launch_bounds__(256) void finalize_kernel(
    const int* __restrict__ types, const float* __restrict__ res_mask,
    const float* __restrict__ mask,
    const float* __restrict__ fape_part, const float* __restrict__ clash_part,
    const float* __restrict__ pen_part,
    float* __restrict__ out, int R, int A) {
  const int tid = threadIdx.x;
  double sf = 0.0, sc0 = 0.0, sc1 = 0.0, sp0 = 0.0, sp1 = 0.0;
  for (int i = tid; i < NB_FAPE; i += 256) sf += (double)fape_part[i];
  for (int p = tid; p < NB_PAIR; p += 256) {
    const int bb = (p < NB_BAND) ? (p >> 8) : ((p - NB_BAND) / 384);
    const double c = (double)clash_part[p];
    const double pe = (double)pen_part[p];
    if (bb == 0) { sc0 += c; sp0 += pe; } else { sc1 += c; sp1 += pe; }
  }
  float cc0 = 0, cn0 = 0, cc1 = 0, cn1 = 0, sm = 0, srm = 0;
  for (int a = tid; a < A; a += 256) {
    const int t0 = types[a], t1 = types[A + a];
    cc0 += (t0 == 0) ? 1.f : 0.f;
    cn0 += (t0 == 1) ? 1.f : 0.f;
    cc1 += (t1 == 0) ? 1.f : 0.f;
    cn1 += (t1 == 1) ? 1.f : 0.f;
    sm += mask[a] + mask[A + a];
  }
  for (int r = tid; r < R; r += 256) srm += res_mask[r] + res_mask[R + r];

  __shared__ double dred[5][4];
  __shared__ float fred[6][4];
  double dv[5] = {sf, sc0, sc1, sp0, sp1};
  float fv[6] = {cc0, cn0, cc1, cn1, sm, srm};
#pragma unroll
  for (int k = 0; k < 5; ++k) {
    const double v = wredd(dv[k]);
    if ((tid & 63) == 0) dred[k][tid >> 6] = v;
  }
#pragma unroll
  for (int k = 0; k < 6; ++k) {
    const float v = wred(fv[k]);
    if ((tid & 63) == 0) fred[k][tid >> 6] = v;
  }
  __syncthreads();
  if (tid == 0) {
    double D[5];
    float F[6];
#pragma unroll
    for (int k = 0; k < 5; ++k) D[k] = dred[k][0] + dred[k][1] + dred[k][2] + dred[k][3];
#pragma unroll
    for (int k = 0; k < 6; ++k) F[k] = fred[k][0] + fred[k][1] + fred[k][2] + fred[k][3];
    const double fape = D[0] / ((double)F[4] * (double)F[5] + 1e-8);
    const double clash = (D[1] + D[2]) / (4.0 * (double)A);  // mean_b((cnt/2)/A), B=2
    const double np0 = fmax((double)F[0] * (double)F[1], 1.0);
    const double np1 = fmax((double)F[2] * (double)F[3], 1.0);
    const double phys = 0.5 * (D[3] / np0 + D[4] / np1);
    out[0] = (float)(fape + 0.05 * clash + 0.3 * phys);
  }
}

extern "C" void kernel_launch(void* const* d_in, const int* in_sizes, int n_in,
                              void* d_out, int out_size, void* d_ws, size_t ws_size,
                              hipStream_t stream) {
  const float* rots_p   = (const float*)d_in[0];
  const float* trans_p  = (const float*)d_in[1];
  const float* coords_p = (const float*)d_in[2];
  const float* rots_t   = (const float*)d_in[3];
  const float* trans_t  = (const float*)d_in[4];
  const float* coords_t = (const float*)d_in[5];
  const int*   types    = (const int*)d_in[6];
  const float* vdw      = (const float*)d_in[7];
  const float* res_mask = (const float*)d_in[8];
  const float* mask     = (const float*)d_in[9];
  float* out = (float*)d_out;

  const int R = in_sizes[8] / BB;  // 1024
  const int A = in_sizes[9] / BB;  // 4096

  float* fape_part  = (float*)d_ws;
  float* clash_part = fape_part + NB_FAPE;
  float* pen_part   = clash_part + NB_PAIR;

  fat_kernel<<<NB_FAPE + NB_PAIR, 256, 0, stream>>>(
      rots_p, trans_p, coords_p, rots_t, trans_t, coords_t, types, vdw,
      res_mask, mask, fape_part, clash_part, pen_part, R, A);

  finalize_kernel<<<1, 256, 0, stream>>>(
      types, res_mask, mask, fape_part, clash_part, pen_part, out, R, A);
}

// Round 3
// 95.141 us; speedup vs baseline: 1.0114x; 1.0114x over previous
//
#include <hip/hip_runtime.h>

// FAPELoss = fape + 0.05*clash + 0.3*physics  ->  single f32 scalar.
// Harness-fixed shapes: B=2, R=1024, A=4096, 19 vdw radii.
//
// Two dispatches:
//   fat_kernel (2304 blocks = 9*256): bid%9<4 -> FAPE (1024 blocks, FR=2 frames each)
//                                     bid%9>=4 -> pair (512 band + 768 full blocks)
//     Interleaved so VALU-heavy FAPE and latency-heavy pair co-reside on each CU.
//     FR=2 keeps whole-kernel VGPR low (~75) -> high occupancy for latency hiding.
//     Per-block float partials -> ws (written unconditionally; no memset needed).
//   finalize_kernel: 1 block x 1024 threads; partials + type counts + mask sums -> out.
//
// Pair symmetry: d(i,j) bit-symmetric in the reference (commutative adds, identical
// dot order), so each unordered pair is evaluated once: clash weight 2 (band blocks
// use per-pair i<j / i==j weights), pen adds BOTH ordered CN terms via the scalar
// j-class branch (j==N -> pp*cf_i, j==C -> pp*nf_i).
// Clash uses d2 < mind^2 (== d < mind up to sqrt-rounding ties; ~1e-6/pair flip prob).
// (d > EPS) is vacuous: d >= sqrt(1e-12) = 1e-6 > 1e-8.

constexpr int BB = 2;
constexpr int FR = 2;     // frames per FAPE block
constexpr int NI = 4;     // i-atoms per thread (pair)
constexpr int TJ = 16;    // j-tile (pair)
constexpr int IC = 1024;  // i-chunk (pair)

constexpr int NB_FAPE = 1024;  // BB * R / FR
constexpr int NB_BAND = 512;   // BB * (A/IC) * (IC/TJ) = 2*4*64
constexpr int NB_FULL = 768;   // BB * (192+128+64+0)
constexpr int NB_PAIR = NB_BAND + NB_FULL;
constexpr int NB_TOT = NB_FAPE + NB_PAIR;  // 2304 = 9*256

__device__ __forceinline__ float wred(float v) {
#pragma unroll
  for (int o = 32; o > 0; o >>= 1) v += __shfl_down(v, o, 64);
  return v;
}
__device__ __forceinline__ double wredd(double v) {
#pragma unroll
  for (int o = 32; o > 0; o >>= 1) v += __shfl_down(v, o, 64);
  return v;
}

// ---------------- pair body (no LDS: j-atom is wave-uniform -> SGPR broadcast) ----
template <bool BAND>
__device__ __forceinline__ void pair_body(
    const float* __restrict__ coords, const int* __restrict__ types,
    const float* __restrict__ vdw, int A, int b, int ic, int jt, int tid,
    float& out_clash, float& out_pen) {
  const int ibase = ic * IC;
  float xi[NI], yi[NI], zi[NI], qi[NI], ri[NI], cf[NI], nf[NI];
  int ii[NI];
#pragma unroll
  for (int k = 0; k < NI; ++k) {
    ii[k] = ibase + (k << 8) + tid;
    const size_t g = (size_t)b * A + ii[k];
    const float x = coords[g * 3], y = coords[g * 3 + 1], z = coords[g * 3 + 2];
    const int t = types[g];
    xi[k] = x; yi[k] = y; zi[k] = z;
    // match reference sq = ((x*x + y*y) + z*z) without fma contraction
    qi[k] = __fadd_rn(__fadd_rn(__fmul_rn(x, x), __fmul_rn(y, y)), __fmul_rn(z, z));
    ri[k] = vdw[t];
    cf[k] = (t == 0) ? 1.f : 0.f;
    nf[k] = (t == 1) ? 1.f : 0.f;
  }

  int cnt2 = 0, cnt1 = 0;
  float pen = 0.f;
  const int j0 = jt * TJ;
#pragma unroll 4
  for (int jj = 0; jj < TJ; ++jj) {
    const int j = j0 + jj;
    const size_t jg = (size_t)b * A + j;   // uniform -> scalar loads
    const float sx = coords[jg * 3], sy = coords[jg * 3 + 1], sz = coords[jg * 3 + 2];
    const int st = types[jg];
    const float sr = vdw[st];
    const float sq = __fadd_rn(__fadd_rn(__fmul_rn(sx, sx), __fmul_rn(sy, sy)),
                               __fmul_rn(sz, sz));
    float dsq[NI];
#pragma unroll
    for (int k = 0; k < NI; ++k) {
      const float dot = fmaf(zi[k], sz, fmaf(yi[k], sy, xi[k] * sx));
      float d2 = fmaf(-2.f, dot, qi[k] + sq);
      d2 = fmaxf(d2, 1e-12f);
      dsq[k] = d2;
      const float mind = ri[k] + sr;
      const bool c = d2 < mind * mind;
      if (BAND) {
        cnt2 += (c && (ii[k] < j)) ? 1 : 0;
        cnt1 += (c && (ii[k] == j)) ? 1 : 0;
      } else {
        cnt2 += c ? 1 : 0;
      }
    }
    if (st <= 1) {  // j is C (0) or N (1): uniform branch, ~10.5% of j's
      const float* flag = (st == 1) ? cf : nf;  // ordered CN term selector
#pragma unroll
      for (int k = 0; k < NI; ++k) {
        const float dd = __builtin_amdgcn_sqrtf(dsq[k]);
        float pp = fmaxf(fabsf(dd - 1.33f) - 0.2f, 0.f);
        if (BAND) pp = (ii[k] < j) ? pp : 0.f;
        pen = fmaf(pp, flag[k], pen);
      }
    }
  }
  out_clash = 2.f * cnt2 + (float)cnt1;
  out_pen = pen;
}

// ---------------- fused kernel --------------------------------------------------
__global__ __launch_bounds__(256) void fat_kernel(
    const float* __restrict__ rots_p, const float* __restrict__ trans_p,
    const float* __restrict__ coords_p,
    const float* __restrict__ rots_t, const float* __restrict__ trans_t,
    const float* __restrict__ coords_t,
    const int* __restrict__ types, const float* __restrict__ vdw,
    const float* __restrict__ res_mask, const float* __restrict__ mask,
    float* __restrict__ fape_part, float* __restrict__ clash_part,
    float* __restrict__ pen_part, int R, int A) {
  const int tid = threadIdx.x;
  const int bid = blockIdx.x;
  // interleave block types so both phases co-reside on every CU:
  // 2304 = 9*256; r9<4 -> FAPE (4/9*2304 = 1024), r9>=4 -> pair (5/9*2304 = 1280)
  const int g9 = bid / 9;
  const int r9 = bid % 9;
  __shared__ float red[2][4];

  if (r9 < 4) {
    // ---- FAPE: err = min(||Rp^T x - Rt^T y - c||_{+eps}, 10) * mask * res_mask
    const int fbid = g9 * 4 + r9;           // [0, 1024)
    const int bpb = R / FR;                 // 512 blocks per batch
    const int b = fbid / bpb;
    const int r0 = (fbid % bpb) * FR;

    float rp[FR][9], rt[FR][9], cc[FR][3], rm[FR];
#pragma unroll
    for (int f = 0; f < FR; ++f) {
      const size_t fr = (size_t)(b * R + r0 + f);  // uniform -> s_load
      const float* Rp = rots_p + fr * 9;
      const float* Rt = rots_t + fr * 9;
      const float* Tp = trans_p + fr * 3;
      const float* Tt = trans_t + fr * 3;
#pragma unroll
      for (int k = 0; k < 9; ++k) { rp[f][k] = Rp[k]; rt[f][k] = Rt[k]; }
      const float tp0 = Tp[0], tp1 = Tp[1], tp2 = Tp[2];
      const float tt0 = Tt[0], tt1 = Tt[1], tt2 = Tt[2];
#pragma unroll
      for (int i = 0; i < 3; ++i) {
        cc[f][i] = (rp[f][0 + i] * tp0 + rp[f][3 + i] * tp1 + rp[f][6 + i] * tp2)
                 - (rt[f][0 + i] * tt0 + rt[f][3 + i] * tt1 + rt[f][6 + i] * tt2);
      }
      rm[f] = res_mask[fr];
    }

    float facc[FR];
#pragma unroll
    for (int f = 0; f < FR; ++f) facc[f] = 0.f;

    for (int a = tid; a < A; a += 256) {
      const size_t g = (size_t)b * A + a;
      const float x0 = coords_p[g * 3], x1 = coords_p[g * 3 + 1], x2 = coords_p[g * 3 + 2];
      const float y0 = coords_t[g * 3], y1 = coords_t[g * 3 + 1], y2 = coords_t[g * 3 + 2];
      const float m = mask[g];
#pragma unroll
      for (int f = 0; f < FR; ++f) {
        float u0 = fmaf(rp[f][0], x0, -cc[f][0]);
        u0 = fmaf(rp[f][3], x1, u0); u0 = fmaf(rp[f][6], x2, u0);
        u0 = fmaf(-rt[f][0], y0, u0); u0 = fmaf(-rt[f][3], y1, u0); u0 = fmaf(-rt[f][6], y2, u0);
        float u1 = fmaf(rp[f][1], x0, -cc[f][1]);
        u1 = fmaf(rp[f][4], x1, u1); u1 = fmaf(rp[f][7], x2, u1);
        u1 = fmaf(-rt[f][1], y0, u1); u1 = fmaf(-rt[f][4], y1, u1); u1 = fmaf(-rt[f][7], y2, u1);
        float u2 = fmaf(rp[f][2], x0, -cc[f][2]);
        u2 = fmaf(rp[f][5], x1, u2); u2 = fmaf(rp[f][8], x2, u2);
        u2 = fmaf(-rt[f][2], y0, u2); u2 = fmaf(-rt[f][5], y1, u2); u2 = fmaf(-rt[f][8], y2, u2);
        float e2 = fmaf(u0, u0, 1e-8f);
        e2 = fmaf(u1, u1, e2);
        e2 = fmaf(u2, u2, e2);
        float e = __builtin_amdgcn_sqrtf(e2);
        e = fminf(e, 10.0f);
        facc[f] = fmaf(e, m, facc[f]);
      }
    }

    float tot = 0.f;
#pragma unroll
    for (int f = 0; f < FR; ++f) tot = fmaf(facc[f], rm[f], tot);

    tot = wred(tot);
    if ((tid & 63) == 0) red[0][tid >> 6] = tot;
    __syncthreads();
    if (tid == 0) fape_part[fbid] = red[0][0] + red[0][1] + red[0][2] + red[0][3];
    return;
  }

  // ---- pair blocks ----
  const int pbid = g9 * 5 + (r9 - 4);  // [0, 1280)
  int b, ic, jt;
  bool band;
  if (pbid < NB_BAND) {
    band = true;
    b = pbid >> 8;
    const int r = pbid & 255;
    ic = r >> 6;
    jt = (ic << 6) + (r & 63);        // band: 64*ic <= jt < 64*(ic+1)
  } else {
    const int q = pbid - NB_BAND;
    band = false;
    b = q / 384;
    const int r = q % 384;
    if (r < 192)      { ic = 0; jt = 64 + r; }
    else if (r < 320) { ic = 1; jt = 128 + (r - 192); }
    else              { ic = 2; jt = 192 + (r - 320); }
  }

  float oc, op;
  if (band) pair_body<true >(coords_p, types, vdw, A, b, ic, jt, tid, oc, op);
  else      pair_body<false>(coords_p, types, vdw, A, b, ic, jt, tid, oc, op);

  const float rc = wred(oc);
  const float rpn = wred(op);
  if ((tid & 63) == 0) { red[0][tid >> 6] = rc; red[1][tid >> 6] = rpn; }
  __syncthreads();
  if (tid == 0) {
    clash_part[pbid] = red[0][0] + red[0][1] + red[0][2] + red[0][3];
    pen_part[pbid]   = red[1][0] + red[1][1] + red[1][2] + red[1][3];
  }
}

// ---------------- finalize (1 block x 1024 threads) -----------------------------
__global__ __launch_bounds__(1024) void finalize_kernel(
    const int* __restrict__ types, const float* __restrict__ res_mask,
    const float* __restrict__ mask,
    const float* __restrict__ fape_part, const float* __restrict__ clash_part,
    const float* __restrict__ pen_part,
    float* __restrict__ out, int R, int A) {
  const int tid = threadIdx.x;
  double sf = 0.0, sc0 = 0.0, sc1 = 0.0, sp0 = 0.0, sp1 = 0.0;
  for (int i = tid; i < NB_FAPE; i += 1024) sf += (double)fape_part[i];
  for (int p = tid; p < NB_PAIR; p += 1024) {
    const int bb = (p < NB_BAND) ? (p >> 8) : ((p - NB_BAND) / 384);
    const double c = (double)clash_part[p];
    const double pe = (double)pen_part[p];
    if (bb == 0) { sc0 += c; sp0 += pe; } else { sc1 += c; sp1 += pe; }
  }
  float cc0 = 0, cn0 = 0, cc1 = 0, cn1 = 0, sm = 0, srm = 0;
  for (int a = tid; a < A; a += 1024) {
    const int t0 = types[a], t1 = types[A + a];
    cc0 += (t0 == 0) ? 1.f : 0.f;
    cn0 += (t0 == 1) ? 1.f : 0.f;
    cc1 += (t1 == 0) ? 1.f : 0.f;
    cn1 += (t1 == 1) ? 1.f : 0.f;
    sm += mask[a] + mask[A + a];
  }
  for (int r = tid; r < R; r += 1024) srm += res_mask[r] + res_mask[R + r];

  __shared__ double dred[5][16];
  __shared__ float fred[6][16];
  double dv[5] = {sf, sc0, sc1, sp0, sp1};
  float fv[6] = {cc0, cn0, cc1, cn1, sm, srm};
#pragma unroll
  for (int k = 0; k < 5; ++k) {
    const double v = wredd(dv[k]);
    if ((tid & 63) == 0) dred[k][tid >> 6] = v;
  }
#pragma unroll
  for (int k = 0; k < 6; ++k) {
    const float v = wred(fv[k]);
    if ((tid & 63) == 0) fred[k][tid >> 6] = v;
  }
  __syncthreads();
  if (tid == 0) {
    double D[5];
    float F[6];
#pragma unroll
    for (int k = 0; k < 5; ++k) {
      double s = 0.0;
#pragma unroll
      for (int w = 0; w < 16; ++w) s += dred[k][w];
      D[k] = s;
    }
#pragma unroll
    for (int k = 0; k < 6; ++k) {
      float s = 0.f;
#pragma unroll
      for (int w = 0; w < 16; ++w) s += fred[k][w];
      F[k] = s;
    }
    const double fape = D[0] / ((double)F[4] * (double)F[5] + 1e-8);
    const double clash = (D[1] + D[2]) / (4.0 * (double)A);  // mean_b((cnt/2)/A), B=2
    const double np0 = fmax((double)F[0] * (double)F[1], 1.0);
    const double np1 = fmax((double)F[2] * (double)F[3], 1.0);
    const double phys = 0.5 * (D[3] / np0 + D[4] / np1);
    out[0] = (float)(fape + 0.05 * clash + 0.3 * phys);
  }
}

extern "C" void kernel_launch(void* const* d_in, const int* in_sizes, int n_in,
                              void* d_out, int out_size, void* d_ws, size_t ws_size,
                              hipStream_t stream) {
  const float* rots_p   = (const float*)d_in[0];
  const float* trans_p  = (const float*)d_in[1];
  const float* coords_p = (const float*)d_in[2];
  const float* rots_t   = (const float*)d_in[3];
  const float* trans_t  = (const float*)d_in[4];
  const float* coords_t = (const float*)d_in[5];
  const int*   types    = (const int*)d_in[6];
  const float* vdw      = (const float*)d_in[7];
  const float* res_mask = (const float*)d_in[8];
  const float* mask     = (const float*)d_in[9];
  float* out = (float*)d_out;

  const int R = in_sizes[8] / BB;  // 1024
  const int A = in_sizes[9] / BB;  // 4096

  float* fape_part  = (float*)d_ws;
  float* clash_part = fape_part + NB_FAPE;
  float* pen_part   = clash_part + NB_PAIR;

  fat_kernel<<<NB_TOT, 256, 0, stream>>>(
      rots_p, trans_p, coords_p, rots_t, trans_t, coords_t, types, vdw,
      res_mask, mask, fape_part, clash_part, pen_part, R, A);

  finalize_kernel<<<1, 1024, 0, stream>>>(
      types, res_mask, mask, fape_part, clash_part, pen_part, out, R, A);
}